// Round 10
// baseline (54.028 us; speedup 1.0000x reference)
//
#include <hip/hip_runtime.h>

#define NN 4096
#define FIN 128
#define NHEAD 4
#define NHID 16
#define NCOL 64
#define SLOPE 0.2f
#define NCH 64      // chunks of 64 ranks

__device__ __forceinline__ float lrelu(float v){ return v > 0.f ? v : SLOPE * v; }

// float bits -> order-preserving unsigned
__device__ __forceinline__ unsigned fkey(float f){
  unsigned b = __float_as_uint(f);
  return b ^ ((b & 0x80000000u) ? 0xFFFFFFFFu : 0x80000000u);
}
__device__ __forceinline__ float fkey_inv(unsigned k){
  unsigned b = (k & 0x80000000u) ? (k ^ 0x80000000u) : ~k;
  return __uint_as_float(b);
}
// padded LDS index for rank r (65-wide rows kill stride-64 bank conflicts)
__device__ __forceinline__ int pidx(int r){ return (r >> 6) * 65 + (r & 63); }

// K1: h = x@W (4096x128 @ 128x64) + fused src/dst epilogue. 512 blocks x 8 rows.
__global__ __launch_bounds__(256) void gemm_h_k(const float* __restrict__ x,
                                                const float* __restrict__ W,
                                                const float* __restrict__ aw,
                                                float* __restrict__ h,
                                                float* __restrict__ src,
                                                float* __restrict__ dst){
  __shared__ __align__(16) float wl[FIN][NCOL];  // 32 KB
  __shared__ float xlT[FIN][10];                 // transposed x tile, pad 10
  __shared__ float hs[8][NCOL + 1];
  int t = threadIdx.x;
  int row0 = blockIdx.x * 8;
  for (int k4 = t; k4 < FIN * NCOL / 4; k4 += 256)
    ((float4*)&wl[0][0])[k4] = ((const float4*)W)[k4];
  for (int k = t; k < 8 * FIN; k += 256){
    int r = k >> 7, d = k & 127;
    xlT[d][r] = x[(row0 + r) * FIN + d];
  }
  __syncthreads();
  int col = t & 63, rb = t >> 6;                 // rb wave-uniform
  float a0 = 0.f, a1 = 0.f;
  #pragma unroll
  for (int d = 0; d < FIN; ++d){
    float wv = wl[d][col];                       // 2-way alias: free
    float2 xv = *(const float2*)&xlT[d][rb * 2]; // wave-uniform broadcast
    a0 = fmaf(xv.x, wv, a0);
    a1 = fmaf(xv.y, wv, a1);
  }
  h[(row0 + rb * 2) * NCOL + col] = a0;     hs[rb * 2][col] = a0;
  h[(row0 + rb * 2 + 1) * NCOL + col] = a1; hs[rb * 2 + 1][col] = a1;
  __syncthreads();
  if (t < 32){
    int r = t >> 2, hd = t & 3;
    float s = 0.f, d = 0.f;
    #pragma unroll
    for (int f = 0; f < NHID; ++f){
      float v = hs[r][hd * NHID + f];
      s = fmaf(v, aw[f], s);
      d = fmaf(v, aw[NHID + f], d);
    }
    src[hd * NN + row0 + r] = s;
    dst[hd * NN + row0 + r] = d;
  }
}

// K2: register-tiled rank-by-counting + scatter. 64 i-blocks x 4 heads, 512 thr.
__global__ __launch_bounds__(512) void ranksc_k(const float* __restrict__ dst,
                                                unsigned long long* __restrict__ ksort){
  int ib = blockIdx.x;   // 0..63 -> 64 i's each
  int hd = blockIdx.y;   // 0..3
  __shared__ __align__(16) unsigned long long keys2[64][66];  // 33.8 KB
  __shared__ int wsum[8][64];
  int t = threadIdx.x;
  const float* dp = dst + hd * NN;
  for (int j = t; j < NN; j += 512)
    keys2[j >> 6][j & 63] = ((unsigned long long)fkey(dp[j]) << 32) | (unsigned)j;
  __syncthreads();
  int g = t >> 3, c = t & 7;           // g: j-row (64 j's); c: i-set (8 i's)
  unsigned long long mk[8];
  #pragma unroll
  for (int r = 0; r < 8; ++r) mk[r] = keys2[ib][c * 8 + r];
  int cnt[8] = {0, 0, 0, 0, 0, 0, 0, 0};
  const ulonglong2* kp = (const ulonglong2*)&keys2[g][0];
  #pragma unroll 4
  for (int q = 0; q < 32; ++q){
    ulonglong2 kk = kp[q];
    #pragma unroll
    for (int r = 0; r < 8; ++r){
      cnt[r] += (kk.x < mk[r]) ? 1 : 0;
      cnt[r] += (kk.y < mk[r]) ? 1 : 0;
    }
  }
  #pragma unroll
  for (int r = 0; r < 8; ++r){
    cnt[r] += __shfl_down(cnt[r], 32);
    cnt[r] += __shfl_down(cnt[r], 16);
    cnt[r] += __shfl_down(cnt[r], 8);
  }
  int w = t >> 6;
  if ((t & 63) < 8){
    #pragma unroll
    for (int r = 0; r < 8; ++r) wsum[w][c * 8 + r] = cnt[r];
  }
  __syncthreads();
  if (t < 64){
    int rank = 0;
    #pragma unroll
    for (int w2 = 0; w2 < 8; ++w2) rank += wsum[w2][t];
    ksort[hd * NN + rank] = keys2[ib][t];   // unique rank (idx breaks ties)
  }
}

// K3: fused chunk-totals + scan + binary-search + combine.
// 256 blocks = (64 i-groups x 4 heads); each block redundantly computes all
// chunk totals for its head from ksort + h, scans them in LDS, then finishes
// its 64 (i,head) pairs with <=64-row in-chunk partials.
__global__ __launch_bounds__(256) void scanout_k(const float* __restrict__ h,
                                                 const float* __restrict__ src,
                                                 const unsigned long long* __restrict__ ksort,
                                                 float* __restrict__ out){
  __shared__ __align__(16) unsigned long long dk[NCH * 65];  // 33.3 KB padded
  __shared__ float e02p[NCH * 65];                           // 16.6 KB padded
  __shared__ float ctP[NCH + 1][20], ctS[NCH + 1][20];       // 10.4 KB (col16=den)
  int t = threadIdx.x;
  int hd = blockIdx.x & 3, ig = blockIdx.x >> 2;
  const unsigned long long* kp = ksort + hd * NN;

  // stage sorted keys (padded rows)
  for (int j = t; j < NN; j += 256) dk[pidx(j)] = kp[j];
  __syncthreads();
  // e^{0.2 d} per rank
  for (int j = t; j < NN; j += 256){
    int pi = pidx(j);
    e02p[pi] = __expf(0.2f * fkey_inv((unsigned)(dk[pi] >> 32)));
  }
  __syncthreads();

  // chunk totals: thread (ch = t>>2, q = t&3) accumulates 64 rows x 4 cols
  {
    int ch = t >> 2, q = t & 3;
    float4 aP = {0.f, 0.f, 0.f, 0.f}, aS = {0.f, 0.f, 0.f, 0.f};
    float dP = 0.f, dS = 0.f;
    int base = ch * 65;
    #pragma unroll 4
    for (int rr = 0; rr < 64; ++rr){
      unsigned long long key = dk[base + rr];
      float e  = e02p[base + rr];
      float p2 = e * e, p4 = p2 * p2;
      float e1 = p4 * e;                       // e^d = (e^{0.2d})^5
      const float4 hv = *(const float4*)(h + (size_t)(unsigned)key * NCOL + hd * NHID + q * 4);
      aP.x = fmaf(e, hv.x, aP.x);  aP.y = fmaf(e, hv.y, aP.y);
      aP.z = fmaf(e, hv.z, aP.z);  aP.w = fmaf(e, hv.w, aP.w);
      aS.x = fmaf(e1, hv.x, aS.x); aS.y = fmaf(e1, hv.y, aS.y);
      aS.z = fmaf(e1, hv.z, aS.z); aS.w = fmaf(e1, hv.w, aS.w);
      dP += e; dS += e1;
    }
    *(float4*)&ctP[ch][q * 4] = aP;
    *(float4*)&ctS[ch][q * 4] = aS;
    if (q == 3){ ctP[ch][16] = dP; ctS[ch][16] = dS; }
  }
  __syncthreads();

  // in-place scans over chunks: ctP -> exclusive prefix (+ totals row 64),
  // ctS -> exclusive suffix (row 64 = 0)
  if (t < 17){
    float run = 0.f;
    #pragma unroll
    for (int c = 0; c < NCH; ++c){ float v = ctP[c][t]; ctP[c][t] = run; run += v; }
    ctP[NCH][t] = run;
  } else if (t >= 64 && t < 81){
    int col = t - 64;
    float rs = 0.f;
    #pragma unroll
    for (int c = NCH - 1; c >= 0; --c){ float v = ctS[c][col]; ctS[c][col] = rs; rs += v; }
    ctS[NCH][col] = 0.f;
  }
  __syncthreads();

  // pairs: binary search kink + in-chunk partials + combine
  {
    int pr = t >> 2, q = t & 3;
    int i = ig * 64 + pr;
    float s = src[hd * NN + i];
    unsigned long long kk = ((unsigned long long)fkey(-s)) << 32;
    int lo = 0, hi = NN;
    while (lo < hi){
      int mid = (lo + hi) >> 1;
      if (dk[pidx(mid)] < kk) lo = mid + 1; else hi = mid;
    }
    int k = lo;                                 // ranks < k take the 0.2 branch
    int ch = k >> 6;                            // may be NCH when k == NN
    float4 aP = {0.f, 0.f, 0.f, 0.f}, aS = {0.f, 0.f, 0.f, 0.f};
    float dP = 0.f, dS = 0.f;
    for (int r = ch * 64; r < k; ++r){          // P side: [64ch, k)
      int pi = pidx(r);
      float e = e02p[pi];
      const float4 hv = *(const float4*)(h + (size_t)(unsigned)dk[pi] * NCOL + hd * NHID + q * 4);
      aP.x = fmaf(e, hv.x, aP.x);  aP.y = fmaf(e, hv.y, aP.y);
      aP.z = fmaf(e, hv.z, aP.z);  aP.w = fmaf(e, hv.w, aP.w);
      dP += e;
    }
    int rend = (ch + 1) * 64; if (rend > NN) rend = NN;
    for (int r = k; r < rend; ++r){             // S side: [k, chunk end)
      int pi = pidx(r);
      float e = e02p[pi];
      float p2 = e * e, p4 = p2 * p2;
      float e1 = p4 * e;
      const float4 hv = *(const float4*)(h + (size_t)(unsigned)dk[pi] * NCOL + hd * NHID + q * 4);
      aS.x = fmaf(e1, hv.x, aS.x); aS.y = fmaf(e1, hv.y, aS.y);
      aS.z = fmaf(e1, hv.z, aS.z); aS.w = fmaf(e1, hv.w, aS.w);
      dS += e1;
    }
    float dmax = fkey_inv((unsigned)(dk[pidx(NN - 1)] >> 32));
    float m = lrelu(s + dmax);
    float alpha = __expf(0.2f * s - m);
    float beta  = __expf(s - m);
    float den = alpha * (ctP[ch][16] + dP) + beta * (ctS[ch][16] + dS);
    float inv = 1.0f / den;
    float4 res;
    res.x = (alpha * (ctP[ch][q * 4 + 0] + aP.x) + beta * (ctS[ch][q * 4 + 0] + aS.x)) * inv;
    res.y = (alpha * (ctP[ch][q * 4 + 1] + aP.y) + beta * (ctS[ch][q * 4 + 1] + aS.y)) * inv;
    res.z = (alpha * (ctP[ch][q * 4 + 2] + aP.z) + beta * (ctS[ch][q * 4 + 2] + aS.z)) * inv;
    res.w = (alpha * (ctP[ch][q * 4 + 3] + aP.w) + beta * (ctS[ch][q * 4 + 3] + aS.w)) * inv;
    *(float4*)(out + (size_t)i * NCOL + hd * NHID + q * 4) = res;
  }
}

extern "C" void kernel_launch(void* const* d_in, const int* in_sizes, int n_in,
                              void* d_out, int out_size, void* d_ws, size_t ws_size,
                              hipStream_t stream){
  const float* x  = (const float*)d_in[0];
  // d_in[1] = adj : UNUSED by the reference (no masking) — never read it.
  const float* W  = (const float*)d_in[2];
  const float* aw = (const float*)d_in[3];
  float* out = (float*)d_out;
  float* ws  = (float*)d_ws;

  float*              h     = ws;                                 // 262144 floats
  float*              src   = ws + 262144;                        // 16384
  float*              dst   = ws + 278528;                        // 16384
  unsigned long long* ksort = (unsigned long long*)(ws + 294912); // 16384 u64 (16B aligned)
  // total ~1.3 MB

  gemm_h_k<<<512, 256, 0, stream>>>(x, W, aw, h, src, dst);
  ranksc_k<<<dim3(64, NHEAD), 512, 0, stream>>>(dst, ksort);
  scanout_k<<<256, 256, 0, stream>>>(h, src, ksort, out);
}

// Round 11
// 28.401 us; speedup vs baseline: 1.9023x; 1.9023x over previous
//
#include <hip/hip_runtime.h>

#define NN 4096
#define FIN 128
#define NHEAD 4
#define NHID 16
#define NCOL 64
#define SLOPE 0.2f
#define CHUNK 64
#define NCH 64      // NN / CHUNK
#define NCOLS 17    // 16 value cols + denominator col
#define RPAD 20     // padded row stride for PL2/SL2 (17 -> 20, float4-friendly)

__device__ __forceinline__ float lrelu(float v){ return v > 0.f ? v : SLOPE * v; }

// float bits -> order-preserving unsigned
__device__ __forceinline__ unsigned fkey(float f){
  unsigned b = __float_as_uint(f);
  return b ^ ((b & 0x80000000u) ? 0xFFFFFFFFu : 0x80000000u);
}
__device__ __forceinline__ float fkey_inv(unsigned k){
  unsigned b = (k & 0x80000000u) ? (k ^ 0x80000000u) : ~k;
  return __uint_as_float(b);
}

// K1: h = x@W (4096x128 @ 128x64) + fused src/dst epilogue. 512 blocks x 8 rows.
__global__ __launch_bounds__(256) void gemm_h_k(const float* __restrict__ x,
                                                const float* __restrict__ W,
                                                const float* __restrict__ aw,
                                                float* __restrict__ h,
                                                float* __restrict__ src,
                                                float* __restrict__ dst){
  __shared__ __align__(16) float wl[FIN][NCOL];  // 32 KB, same layout as W
  __shared__ float xlT[FIN][10];                 // transposed x tile, pad 10
  __shared__ float hs[8][NCOL + 1];
  int t = threadIdx.x;
  int row0 = blockIdx.x * 8;
  for (int k4 = t; k4 < FIN * NCOL / 4; k4 += 256)
    ((float4*)&wl[0][0])[k4] = ((const float4*)W)[k4];
  for (int k = t; k < 8 * FIN; k += 256){
    int r = k >> 7, d = k & 127;
    xlT[d][r] = x[(row0 + r) * FIN + d];         // coalesced global, stride-10 LDS
  }
  __syncthreads();
  int col = t & 63, rb = t >> 6;                 // rb wave-uniform
  float a0 = 0.f, a1 = 0.f;
  #pragma unroll
  for (int d = 0; d < FIN; ++d){
    float wv = wl[d][col];                       // 2-way alias: free
    float2 xv = *(const float2*)&xlT[d][rb * 2]; // wave-uniform b64 broadcast
    a0 = fmaf(xv.x, wv, a0);
    a1 = fmaf(xv.y, wv, a1);
  }
  h[(row0 + rb * 2) * NCOL + col] = a0;     hs[rb * 2][col] = a0;
  h[(row0 + rb * 2 + 1) * NCOL + col] = a1; hs[rb * 2 + 1][col] = a1;
  __syncthreads();
  if (t < 32){
    int r = t >> 2, hd = t & 3;
    float s = 0.f, d = 0.f;
    #pragma unroll
    for (int f = 0; f < NHID; ++f){
      float v = hs[r][hd * NHID + f];
      s = fmaf(v, aw[f], s);
      d = fmaf(v, aw[NHID + f], d);
    }
    src[hd * NN + row0 + r] = s;
    dst[hd * NN + row0 + r] = d;
  }
}

// K2: register-tiled rank-by-counting + scatter. 128 i-blocks x 4 heads, 512 thr,
// 32 i's per block -> 2 blocks/CU (2 waves/SIMD) for latency overlap.
// Thread (g=t>>3, c=t&7): counts row g's 64 j-keys against 4 i-keys (c*4+r).
__global__ __launch_bounds__(512) void ranksc_k(const float* __restrict__ dst,
                                                unsigned long long* __restrict__ ksort,
                                                unsigned* __restrict__ dkey){
  int ib = blockIdx.x;   // 0..127 -> 32 i's each
  int hd = blockIdx.y;   // 0..3
  __shared__ __align__(16) unsigned long long keys2[64][66];  // 33.8 KB
  __shared__ int wsum[8][32];
  int t = threadIdx.x;
  const float* dp = dst + hd * NN;
  for (int j = t; j < NN; j += 512)
    keys2[j >> 6][j & 63] = ((unsigned long long)fkey(dp[j]) << 32) | (unsigned)j;
  __syncthreads();
  int g = t >> 3, c = t & 7;           // g: j-row (64 j's); c: i-set (4 i's)
  unsigned long long mk[4];
  #pragma unroll
  for (int r = 0; r < 4; ++r){
    int i = ib * 32 + c * 4 + r;
    mk[r] = keys2[i >> 6][i & 63];
  }
  int cnt[4] = {0, 0, 0, 0};
  const ulonglong2* kp = (const ulonglong2*)&keys2[g][0];
  #pragma unroll 4
  for (int q = 0; q < 32; ++q){
    ulonglong2 kk = kp[q];
    #pragma unroll
    for (int r = 0; r < 4; ++r){
      cnt[r] += (kk.x < mk[r]) ? 1 : 0;
      cnt[r] += (kk.y < mk[r]) ? 1 : 0;
    }
  }
  // reduce over the wave's 8 g-rows (lanes with equal c are 8 apart)
  #pragma unroll
  for (int r = 0; r < 4; ++r){
    cnt[r] += __shfl_down(cnt[r], 32);
    cnt[r] += __shfl_down(cnt[r], 16);
    cnt[r] += __shfl_down(cnt[r], 8);
  }
  int w = t >> 6;                      // wave id 0..7
  if ((t & 63) < 8){
    #pragma unroll
    for (int r = 0; r < 4; ++r) wsum[w][c * 4 + r] = cnt[r];
  }
  __syncthreads();
  if (t < 32){
    int rank = 0;
    #pragma unroll
    for (int w2 = 0; w2 < 8; ++w2) rank += wsum[w2][t];
    int i = ib * 32 + t;
    unsigned long long key = keys2[i >> 6][i & 63];
    ksort[hd * NN + rank] = key;       // unique rank (idx breaks ties)
    dkey[hd * NN + rank]  = (unsigned)(key >> 32);
  }
}

// K3: per-(head,chunk) local prefix/suffix scans -> transposed padded PL2/SL2.
__global__ __launch_bounds__(256) void scanA_k(const float* __restrict__ h,
                                               const unsigned long long* __restrict__ ksort,
                                               float* __restrict__ PL2,
                                               float* __restrict__ SL2,
                                               float* __restrict__ ctP,
                                               float* __restrict__ ctS){
  int ch = blockIdx.x;   // 64
  int hd = blockIdx.y;   // 4
  int t = threadIdx.x;
  int base = ch * CHUNK;
  __shared__ float e02[CHUNK], e1[CHUNK];
  __shared__ int   pms[CHUNK];
  __shared__ float hl[CHUNK][RPAD];
  __shared__ float PLs[CHUNK][RPAD], SLs[CHUNK][RPAD];
  if (t < CHUNK){
    unsigned long long key = ksort[hd * NN + base + t];
    float d = fkey_inv((unsigned)(key >> 32));
    e02[t] = __expf(0.2f * d);
    e1[t]  = __expf(d);
    pms[t] = (int)(unsigned)key;
    hl[t][16] = 1.0f;
  }
  __syncthreads();
  {
    int col = t & 15, r0 = t >> 4;
    #pragma unroll
    for (int it = 0; it < 4; ++it){
      int r = it * 16 + r0;
      hl[r][col] = h[pms[r] * NCOL + hd * NHID + col];
    }
  }
  __syncthreads();
  if (t < NCOLS){
    int col = t;
    float run = 0.f;
    #pragma unroll
    for (int r = 0; r < CHUNK; ++r){
      PLs[r][col] = run;                        // exclusive
      run = fmaf(e02[r], hl[r][col], run);
    }
    ctP[ch * 68 + hd * 17 + col] = run;
  } else if (t >= 64 && t < 64 + NCOLS){
    int col = t - 64;
    float rs = 0.f;
    #pragma unroll
    for (int r = CHUNK - 1; r >= 0; --r){
      rs = fmaf(e1[r], hl[r][col], rs);
      SLs[r][col] = rs;                         // inclusive
    }
    ctS[ch * 68 + hd * 17 + col] = rs;
  }
  __syncthreads();
  // contiguous coalesced writes (pad cols carry garbage, never read)
  #pragma unroll
  for (int n = 0; n < 5; ++n){
    int idx = n * 256 + t;                      // 5*256 = 64*20
    int r = idx / RPAD, c = idx % RPAD;
    PL2[(hd * NN + base + r) * RPAD + c] = PLs[r][c];
    SL2[(hd * NN + base + r) * RPAD + c] = SLs[r][c];
  }
}

// K4: LDS ct-scan + LDS binary search + float4 combine. 256 blocks x 64 pairs.
__global__ __launch_bounds__(256) void out_k(const float* __restrict__ src,
                                             const unsigned* __restrict__ dkey,
                                             const float* __restrict__ PL2,
                                             const float* __restrict__ SL2,
                                             const float* __restrict__ ctP,
                                             const float* __restrict__ ctS,
                                             float* __restrict__ out){
  __shared__ __align__(16) unsigned dk[NN];        // 16 KB sorted keys
  __shared__ __align__(16) float oP[NCH + 1][68];  // 17.7 KB (row NCH = totals)
  __shared__ __align__(16) float oS[NCH][68];      // 17.4 KB
  int t = threadIdx.x;
  int hd = blockIdx.x & 3, ig = blockIdx.x >> 2;
  const unsigned* dkp = dkey + hd * NN;
  #pragma unroll
  for (int n = 0; n < 4; ++n)
    ((uint4*)dk)[n * 256 + t] = ((const uint4*)dkp)[n * 256 + t];
  #pragma unroll
  for (int n = 0; n < 5; ++n){
    int idx = n * 256 + t;
    if (idx < 1088){
      ((float4*)&oP[0][0])[idx] = ((const float4*)ctP)[idx];
      ((float4*)&oS[0][0])[idx] = ((const float4*)ctS)[idx];
    }
  }
  __syncthreads();
  if (t < 68){
    float run = 0.f;
    #pragma unroll
    for (int c = 0; c < NCH; ++c){ float v = oP[c][t]; oP[c][t] = run; run += v; }
    oP[NCH][t] = run;
  } else if (t >= 128 && t < 196){
    int cc = t - 128;
    float rs = 0.f;
    #pragma unroll
    for (int c = NCH - 1; c >= 0; --c){ float v = oS[c][cc]; oS[c][cc] = rs; rs += v; }
  }
  __syncthreads();
  int p = t >> 2, q = t & 3;            // 64 pairs x 4 threads
  int i = ig * 64 + p;
  float s = src[hd * NN + i];
  unsigned tu = fkey(-s);
  int lo = 0, hi = NN;
  while (lo < hi){                      // 12 LDS-latency hops
    int mid = (lo + hi) >> 1;
    if (dk[mid] < tu) lo = mid + 1; else hi = mid;
  }
  int k = lo;                           // ranks < k take the 0.2 branch
  float4 res;
  if (k == NN){                         // all in 0.2 branch: alpha cancels
    float inv = 1.0f / oP[NCH][hd * 17 + 16];
    res.x = oP[NCH][hd * 17 + q * 4 + 0] * inv;
    res.y = oP[NCH][hd * 17 + q * 4 + 1] * inv;
    res.z = oP[NCH][hd * 17 + q * 4 + 2] * inv;
    res.w = oP[NCH][hd * 17 + q * 4 + 3] * inv;
  } else {
    float dmax = fkey_inv(dk[NN - 1]);
    float m = lrelu(s + dmax);
    float alpha = __expf(0.2f * s - m);
    float beta  = __expf(s - m);
    int ch = k >> 6;
    const float* P2 = PL2 + (size_t)(hd * NN + k) * RPAD;
    const float* S2 = SL2 + (size_t)(hd * NN + k) * RPAD;
    float4 p4 = *(const float4*)(P2 + q * 4);
    float4 s4 = *(const float4*)(S2 + q * 4);
    float den = alpha * (P2[16] + oP[ch][hd * 17 + 16])
              + beta  * (S2[16] + oS[ch][hd * 17 + 16]);
    float inv = 1.0f / den;
    res.x = (alpha * (p4.x + oP[ch][hd * 17 + q * 4 + 0])
           + beta  * (s4.x + oS[ch][hd * 17 + q * 4 + 0])) * inv;
    res.y = (alpha * (p4.y + oP[ch][hd * 17 + q * 4 + 1])
           + beta  * (s4.y + oS[ch][hd * 17 + q * 4 + 1])) * inv;
    res.z = (alpha * (p4.z + oP[ch][hd * 17 + q * 4 + 2])
           + beta  * (s4.z + oS[ch][hd * 17 + q * 4 + 2])) * inv;
    res.w = (alpha * (p4.w + oP[ch][hd * 17 + q * 4 + 3])
           + beta  * (s4.w + oS[ch][hd * 17 + q * 4 + 3])) * inv;
  }
  *(float4*)(out + i * NCOL + hd * NHID + q * 4) = res;
}

extern "C" void kernel_launch(void* const* d_in, const int* in_sizes, int n_in,
                              void* d_out, int out_size, void* d_ws, size_t ws_size,
                              hipStream_t stream){
  const float* x  = (const float*)d_in[0];
  // d_in[1] = adj : UNUSED by the reference (no masking) — never read it.
  const float* W  = (const float*)d_in[2];
  const float* aw = (const float*)d_in[3];
  float* out = (float*)d_out;
  float* ws  = (float*)d_ws;

  float*              h     = ws;                                   // 262144
  float*              src   = ws + 262144;                          // 16384
  float*              dst   = ws + 278528;                          // 16384
  unsigned long long* ksort = (unsigned long long*)(ws + 294912);   // 16384 u64 (16B-aligned)
  unsigned*           dkey  = (unsigned*)(ws + 327680);             // 16384
  float*              PL2   = ws + 344064;                          // 4*4096*20 = 327680
  float*              SL2   = ws + 671744;                          // 327680
  float*              ctP   = ws + 999424;                          // 4352
  float*              ctS   = ws + 1003776;                         // 4352
  // total ~4.03 MB

  gemm_h_k<<<512, 256, 0, stream>>>(x, W, aw, h, src, dst);
  ranksc_k<<<dim3(128, NHEAD), 512, 0, stream>>>(dst, ksort, dkey);
  scanA_k<<<dim3(NCH, NHEAD), 256, 0, stream>>>(h, ksort, PL2, SL2, ctP, ctS);
  out_k<<<256, 256, 0, stream>>>(src, dkey, PL2, SL2, ctP, ctS, out);
}